// Round 1
// baseline (145.243 us; speedup 1.0000x reference)
//
#include <hip/hip_runtime.h>

// VQ-VAE VectorQuantizer forward, MI355X (gfx950), fp32.
// N=32768 points x D=64 dims, K=1024 codes.
// Out layout: [0]=loss, [1..2097152]=quantized [B,D,H,W], [+..]=indices [B,H*W] as f32.

constexpr int D_   = 64;
constexpr int HW   = 1024;     // H*W = 32*32
constexpr int K_   = 1024;
constexpr int PTS  = 128;      // points per block
constexpr int KC   = 64;       // codes per chunk
constexpr int NCHUNK = K_ / KC;
constexpr int SX   = 132;      // xT row stride (floats), %4==0 for b128
constexpr int SE   = 68;       // eT row stride (floats), %4==0 for b128
constexpr int QE   = 2097152;  // quantized element count
constexpr int IDX_OFF = 1 + QE;

__global__ void vq_e2_kernel(const float* __restrict__ emb,
                             float* __restrict__ e2,
                             float* __restrict__ loss_acc) {
  int k = blockIdx.x * 256 + threadIdx.x;
  if (k == 0) loss_acc[0] = 0.0f;   // zero accumulator (ws is poisoned each call)
  if (k >= K_) return;
  const float4* e4 = (const float4*)(emb + k * 64);
  float s = 0.f;
#pragma unroll
  for (int q = 0; q < 16; ++q) {
    float4 v = e4[q];
    s += v.x * v.x; s += v.y * v.y; s += v.z * v.z; s += v.w * v.w;
  }
  e2[k] = s;
}

__global__ __launch_bounds__(256) void vq_main_kernel(
    const float* __restrict__ in, const float* __restrict__ emb,
    const float* __restrict__ e2g, float* __restrict__ out,
    float* __restrict__ loss_acc) {
  __shared__ float xT[D_ * SX];   // xT[d][p], later overwritten with ST output values
  __shared__ float eT[D_ * SE];   // eT[d][k_local] transposed code chunk
  __shared__ float x2s[PTS];
  __shared__ float e2c[KC];
  __shared__ int   idx_sel[PTS];
  __shared__ float redbuf[4];

  const int t   = threadIdx.x;
  const int tx  = t & 15;         // code group (4 codes)
  const int ty  = t >> 4;         // point group (8 points, split 2x4)
  const int blk = blockIdx.x;
  const int b   = blk >> 3;       // 8 blocks per batch image (1024 hw / 128)
  const int hw0 = (blk & 7) * PTS;
  const float* inb = in + b * (D_ * HW) + hw0;

  // ---- stage x tile -> xT[d][p] (coalesced float4 global, b128 LDS writes) ----
#pragma unroll
  for (int i = 0; i < 8; ++i) {
    int fi = t + i * 256;               // 0..2047
    int d  = fi >> 5, p4 = fi & 31;
    float4 v = *(const float4*)(inb + d * HW + p4 * 4);
    *(float4*)(&xT[d * SX + p4 * 4]) = v;
  }
  __syncthreads();

  // ---- x2[p] = sum_d x^2 (sequential d order) ----
  if (t < PTS) {
    float s = 0.f;
#pragma unroll 8
    for (int d = 0; d < D_; ++d) { float xv = xT[d * SX + t]; s = fmaf(xv, xv, s); }
    x2s[t] = s;
  }
  __syncthreads();

  float x2r[8];
#pragma unroll
  for (int i = 0; i < 8; ++i) {
    int pi = (i < 4) ? ty * 4 + i : 64 + ty * 4 + (i - 4);
    x2r[i] = x2s[pi];
  }
  float minv[8]; int mini[8];
#pragma unroll
  for (int i = 0; i < 8; ++i) { minv[i] = 3.4e38f; mini[i] = 0; }

  // ---- K loop: 16 chunks of 64 codes ----
  for (int c = 0; c < NCHUNK; ++c) {
    const int kb = c * KC;
    // stage transposed eT[d][kl]
#pragma unroll
    for (int i = 0; i < 4; ++i) {
      int fi = t + i * 256;             // 0..1023
      int kl = fi >> 4, d4 = fi & 15;
      float4 v = *(const float4*)(emb + (kb + kl) * 64 + d4 * 4);
      eT[(d4 * 4 + 0) * SE + kl] = v.x;
      eT[(d4 * 4 + 1) * SE + kl] = v.y;
      eT[(d4 * 4 + 2) * SE + kl] = v.z;
      eT[(d4 * 4 + 3) * SE + kl] = v.w;
    }
    if (t < KC) e2c[t] = e2g[kb + t];
    __syncthreads();

    float acc[8][4];
#pragma unroll
    for (int i = 0; i < 8; ++i)
#pragma unroll
      for (int j = 0; j < 4; ++j) acc[i][j] = 0.f;

#pragma unroll 4
    for (int d = 0; d < D_; ++d) {
      float4 xa = *(const float4*)(&xT[d * SX + ty * 4]);        // broadcast-16
      float4 xb = *(const float4*)(&xT[d * SX + 64 + ty * 4]);   // broadcast-16
      float4 ea = *(const float4*)(&eT[d * SE + tx * 4]);        // conflict-free
      float xf[8] = {xa.x, xa.y, xa.z, xa.w, xb.x, xb.y, xb.z, xb.w};
      float ef[4] = {ea.x, ea.y, ea.z, ea.w};
#pragma unroll
      for (int i = 0; i < 8; ++i)
#pragma unroll
        for (int j = 0; j < 4; ++j)
          acc[i][j] = fmaf(xf[i], ef[j], acc[i][j]);
    }

    // fold: u = fl(fl(x2 - 2*dot) + e2)  (matches ref rounding; fmaf == single
    // rounding of x2 - 2*dot since 2*dot is exact)
#pragma unroll
    for (int j = 0; j < 4; ++j) {
      int cl = tx * 4 + j;
      float e2v = e2c[cl];
      int cg = kb + cl;
#pragma unroll
      for (int i = 0; i < 8; ++i) {
        float u = fmaf(-2.f, acc[i][j], x2r[i]) + e2v;
        if (u < minv[i]) { minv[i] = u; mini[i] = cg; }  // strict <: codes ascend per thread
      }
    }
    __syncthreads();
  }

  // ---- cross-thread argmin over the 16 tx lanes sharing each point ----
#pragma unroll
  for (int i = 0; i < 8; ++i) {
    float v = minv[i]; int ix = mini[i];
#pragma unroll
    for (int off = 1; off < 16; off <<= 1) {
      float vo = __shfl_xor(v, off);
      int   io = __shfl_xor(ix, off);
      if (vo < v || (vo == v && io < ix)) { v = vo; ix = io; }  // tie -> lower index
    }
    if (tx == 0) {
      int pi = (i < 4) ? ty * 4 + i : 64 + ty * 4 + (i - 4);
      idx_sel[pi] = ix;
    }
  }
  __syncthreads();

  // indices output (coalesced), as float
  if (t < PTS) out[IDX_OFF + blk * PTS + t] = (float)idx_sel[t];

  // ---- gather selected codes, compute loss partial, overwrite xT with
  //      straight-through value x + (q - x) (replicates ref rounding) ----
  float lp = 0.f;
#pragma unroll
  for (int i = 0; i < 8; ++i) {
    int fi = t + i * 256;               // 0..2047
    int p = fi >> 4, d4 = fi & 15;
    int cidx = idx_sel[p];
    float4 q = *(const float4*)(emb + cidx * 64 + d4 * 4);
    float xv0 = xT[(d4 * 4 + 0) * SX + p];
    float xv1 = xT[(d4 * 4 + 1) * SX + p];
    float xv2 = xT[(d4 * 4 + 2) * SX + p];
    float xv3 = xT[(d4 * 4 + 3) * SX + p];
    float d0 = q.x - xv0, d1 = q.y - xv1, d2 = q.z - xv2, d3 = q.w - xv3;
    lp = fmaf(d0, d0, lp); lp = fmaf(d1, d1, lp);
    lp = fmaf(d2, d2, lp); lp = fmaf(d3, d3, lp);
    xT[(d4 * 4 + 0) * SX + p] = xv0 + d0;
    xT[(d4 * 4 + 1) * SX + p] = xv1 + d1;
    xT[(d4 * 4 + 2) * SX + p] = xv2 + d2;
    xT[(d4 * 4 + 3) * SX + p] = xv3 + d3;
  }

  // loss reduce: wave -> block -> one atomic
#pragma unroll
  for (int off = 1; off < 64; off <<= 1) lp += __shfl_xor(lp, off);
  if ((t & 63) == 0) redbuf[t >> 6] = lp;
  __syncthreads();   // also orders xT rewrites before the output reads below
  if (t == 0) atomicAdd(loss_acc, redbuf[0] + redbuf[1] + redbuf[2] + redbuf[3]);

  // quantized output [B,D,H,W]: out+1 is 4B-aligned only -> scalar coalesced stores
  float* outq = out + 1 + b * (D_ * HW) + hw0;
#pragma unroll
  for (int i = 0; i < 32; ++i) {
    int oi = t + i * 256;               // 0..8191
    int d = oi >> 7, p = oi & 127;
    outq[d * HW + p] = xT[d * SX + p];
  }
}

__global__ void vq_fin_kernel(const float* __restrict__ loss_acc,
                              float* __restrict__ out) {
  float m = loss_acc[0] * (1.0f / 2097152.0f);   // mse
  out[0] = m + 0.25f * m;                        // q_loss + 0.25*e_loss, ref op order
}

extern "C" void kernel_launch(void* const* d_in, const int* in_sizes, int n_in,
                              void* d_out, int out_size, void* d_ws, size_t ws_size,
                              hipStream_t stream) {
  const float* in  = (const float*)d_in[0];
  const float* emb = (const float*)d_in[1];
  float* out = (float*)d_out;
  float* ws  = (float*)d_ws;
  float* loss_acc = ws;        // ws[0]
  float* e2       = ws + 16;   // ws[16..16+1024)

  vq_e2_kernel<<<4, 256, 0, stream>>>(emb, e2, loss_acc);
  vq_main_kernel<<<256, 256, 0, stream>>>(in, emb, e2, out, loss_acc);
  vq_fin_kernel<<<1, 1, 0, stream>>>(loss_acc, out);
}

// Round 2
// 140.081 us; speedup vs baseline: 1.0369x; 1.0369x over previous
//
#include <hip/hip_runtime.h>

// VQ-VAE VectorQuantizer forward, MI355X (gfx950), fp32.
// N=32768 points x D=64 dims, K=1024 codes.
// Out layout: [0]=loss, [1..2097152]=quantized [B,D,H,W], [+..]=indices [B,H*W] as f32.
//
// R2: single fused kernel. grid=256 x 1024 threads (16 waves/CU, 4/SIMD).
// 4 groups of 256 threads split K (4 chunks of 64 codes each); per-(point,code)
// fp32 rounding identical to R1 (which matched np exactly). XOR-swizzled eT
// (stride 64) kills the stride-68 scatter conflicts. e2 recomputed per block
// with R1-identical source; loss finalized by last block (atomic counter).

constexpr int D_   = 64;
constexpr int HW   = 1024;     // H*W = 32*32
constexpr int K_   = 1024;
constexpr int PTS  = 128;      // points per block
constexpr int SX   = 132;      // xT row stride (floats), %4==0 for b128
constexpr int QE   = 2097152;  // quantized element count
constexpr int IDX_OFF = 1 + QE;

__global__ __launch_bounds__(1024) void vq_main_kernel(
    const float* __restrict__ in, const float* __restrict__ emb,
    float* __restrict__ out, float* __restrict__ loss_acc,
    unsigned* __restrict__ cnt) {
  __shared__ float xT[D_ * SX];     // xT[d][p]; later holds straight-through values
  __shared__ float eT[4][D_ * 64];  // per-group swizzled transposed code chunk
  __shared__ float e2s[K_];
  __shared__ float x2s[PTS];
  __shared__ int   idx_sel[PTS];
  __shared__ float cmb_v[4][PTS];
  __shared__ int   cmb_i[4][PTS];
  __shared__ float redbuf[16];

  const int t   = threadIdx.x;
  const int g   = t >> 8;          // K-split group (256 codes each)
  const int tg  = t & 255;
  const int tx  = tg & 15;         // code group (4 codes)
  const int ty  = tg >> 4;         // point group (8 points, split 2x4)
  const int blk = blockIdx.x;
  const int b   = blk >> 3;
  const int hw0 = (blk & 7) * PTS;
  const float* inb = in + b * (D_ * HW) + hw0;

  // ---- stage x tile -> xT[d][p] (coalesced float4, 2-way LDS = free) ----
#pragma unroll
  for (int i = 0; i < 2; ++i) {
    int fi = t + i * 1024;              // 0..2047
    int d  = fi >> 5, p4 = fi & 31;
    *(float4*)(&xT[d * SX + p4 * 4]) = *(const float4*)(inb + d * HW + p4 * 4);
  }

  // ---- e2s[k]: one code per thread, source identical to R1 (rounding!) ----
  {
    const float4* e4 = (const float4*)(emb + t * 64);
    float s = 0.f;
#pragma unroll
    for (int q = 0; q < 16; ++q) {
      float4 v = e4[q];
      s += v.x * v.x; s += v.y * v.y; s += v.z * v.z; s += v.w * v.w;
    }
    e2s[t] = s;
  }
  __syncthreads();

  // ---- x2[p] = sum_d x^2 (sequential d, fmaf chain — identical to R1) ----
  if (t < PTS) {
    float s = 0.f;
#pragma unroll 8
    for (int d = 0; d < D_; ++d) { float xv = xT[d * SX + t]; s = fmaf(xv, xv, s); }
    x2s[t] = s;
  }
  __syncthreads();

  float x2r[8];
#pragma unroll
  for (int i = 0; i < 8; ++i) {
    int pi = (i < 4) ? ty * 4 + i : 64 + ty * 4 + (i - 4);
    x2r[i] = x2s[pi];
  }
  float minv[8]; int mini[8];
#pragma unroll
  for (int i = 0; i < 8; ++i) { minv[i] = 3.4e38f; mini[i] = 0; }

  // ---- K loop: each group handles 4 chunks of 64 codes ----
  for (int c = 0; c < 4; ++c) {
    const int kb = (g * 4 + c) * 64;
    // stage swizzled eT[g]: code kl, dim row -> col ((kl>>2)^(row>>2))*4 + (kl&3)
#pragma unroll
    for (int i = 0; i < 4; ++i) {
      int fi = tg + i * 256;            // 0..1023
      int kl = fi >> 4, d4 = fi & 15;
      float4 v = *(const float4*)(emb + (kb + kl) * 64 + d4 * 4);
      int cpd = (((kl >> 2) ^ d4) << 2) | (kl & 3);
      float* eg = &eT[g][0];
      eg[(d4 * 4 + 0) * 64 + cpd] = v.x;   // 2-way bank alias max = free
      eg[(d4 * 4 + 1) * 64 + cpd] = v.y;
      eg[(d4 * 4 + 2) * 64 + cpd] = v.z;
      eg[(d4 * 4 + 3) * 64 + cpd] = v.w;
    }
    __syncthreads();

    float acc[8][4];
#pragma unroll
    for (int i = 0; i < 8; ++i)
#pragma unroll
      for (int j = 0; j < 4; ++j) acc[i][j] = 0.f;

#pragma unroll 4
    for (int d = 0; d < D_; ++d) {
      float4 xa = *(const float4*)(&xT[d * SX + ty * 4]);        // broadcast
      float4 xb = *(const float4*)(&xT[d * SX + 64 + ty * 4]);   // broadcast
      float4 ea = *(const float4*)(&eT[g][d * 64 + ((tx ^ (d >> 2)) << 2)]); // conflict-free
      float xf[8] = {xa.x, xa.y, xa.z, xa.w, xb.x, xb.y, xb.z, xb.w};
      float ef[4] = {ea.x, ea.y, ea.z, ea.w};
#pragma unroll
      for (int i = 0; i < 8; ++i)
#pragma unroll
        for (int j = 0; j < 4; ++j)
          acc[i][j] = fmaf(xf[i], ef[j], acc[i][j]);
    }

    // fold: u = fl(fl(x2 - 2*dot) + e2) — identical expression to R1
#pragma unroll
    for (int j = 0; j < 4; ++j) {
      int cl = tx * 4 + j;
      float e2v = e2s[kb + cl];
      int cg = kb + cl;
#pragma unroll
      for (int i = 0; i < 8; ++i) {
        float u = fmaf(-2.f, acc[i][j], x2r[i]) + e2v;
        if (u < minv[i]) { minv[i] = u; mini[i] = cg; }  // strict <: codes ascend
      }
    }
    __syncthreads();
  }

  // ---- per-group cross-lane argmin over 16 tx lanes ----
#pragma unroll
  for (int i = 0; i < 8; ++i) {
    float v = minv[i]; int ix = mini[i];
#pragma unroll
    for (int off = 1; off < 16; off <<= 1) {
      float vo = __shfl_xor(v, off);
      int   io = __shfl_xor(ix, off);
      if (vo < v || (vo == v && io < ix)) { v = vo; ix = io; }  // tie -> lower idx
    }
    if (tx == 0) {
      int pi = (i < 4) ? ty * 4 + i : 64 + ty * 4 + (i - 4);
      cmb_v[g][pi] = v; cmb_i[g][pi] = ix;
    }
  }
  __syncthreads();

  // ---- cross-group combine (groups ascend in k: strict < keeps first-min) ----
  if (t < PTS) {
    float v = cmb_v[0][t]; int ix = cmb_i[0][t];
#pragma unroll
    for (int g2 = 1; g2 < 4; ++g2) {
      float vo = cmb_v[g2][t]; int io = cmb_i[g2][t];
      if (vo < v) { v = vo; ix = io; }
    }
    idx_sel[t] = ix;
    out[IDX_OFF + blk * PTS + t] = (float)ix;   // coalesced
  }
  __syncthreads();

  // ---- gather codes, loss partial, overwrite xT with x + (q - x) ----
  float lp = 0.f;
#pragma unroll
  for (int i = 0; i < 2; ++i) {
    int fi = t + i * 1024;              // 0..2047
    int p = fi & 127, qd = fi >> 7;     // p contiguous per wave -> 2-way LDS = free
    int cidx = idx_sel[p];
    float4 q = *(const float4*)(emb + cidx * 64 + qd * 4);
    float xv0 = xT[(qd * 4 + 0) * SX + p];
    float xv1 = xT[(qd * 4 + 1) * SX + p];
    float xv2 = xT[(qd * 4 + 2) * SX + p];
    float xv3 = xT[(qd * 4 + 3) * SX + p];
    float d0 = q.x - xv0, d1 = q.y - xv1, d2 = q.z - xv2, d3 = q.w - xv3;
    lp = fmaf(d0, d0, lp); lp = fmaf(d1, d1, lp);
    lp = fmaf(d2, d2, lp); lp = fmaf(d3, d3, lp);
    xT[(qd * 4 + 0) * SX + p] = xv0 + d0;
    xT[(qd * 4 + 1) * SX + p] = xv1 + d1;
    xT[(qd * 4 + 2) * SX + p] = xv2 + d2;
    xT[(qd * 4 + 3) * SX + p] = xv3 + d3;
  }

  // loss: wave -> block -> one device atomic; last block finalizes out[0]
#pragma unroll
  for (int off = 1; off < 64; off <<= 1) lp += __shfl_xor(lp, off);
  if ((t & 63) == 0) redbuf[t >> 6] = lp;
  __syncthreads();   // also orders xT rewrites before the output reads below
  if (t == 0) {
    float part = 0.f;
#pragma unroll
    for (int w = 0; w < 16; ++w) part += redbuf[w];
    atomicAdd(loss_acc, part);
    __threadfence();
    unsigned old = atomicAdd(cnt, 1u);
    if (old == 255u) {
      __threadfence();
      float total = atomicAdd(loss_acc, 0.0f);  // coherent read-back
      float m = total * (1.0f / 2097152.0f);
      out[0] = m + 0.25f * m;                   // q_loss + 0.25*e_loss, ref op order
    }
  }

  // quantized output [B,D,H,W]: out+1 is 4B-aligned -> scalar coalesced stores
  float* outq = out + 1 + b * (D_ * HW) + hw0;
#pragma unroll
  for (int i = 0; i < 8; ++i) {
    int oi = t + i * 1024;              // 0..8191
    int d = oi >> 7, p = oi & 127;
    outq[d * HW + p] = xT[d * SX + p];
  }
}

extern "C" void kernel_launch(void* const* d_in, const int* in_sizes, int n_in,
                              void* d_out, int out_size, void* d_ws, size_t ws_size,
                              hipStream_t stream) {
  const float* in  = (const float*)d_in[0];
  const float* emb = (const float*)d_in[1];
  float* out = (float*)d_out;
  float* loss_acc = (float*)d_ws;                 // ws[0]
  unsigned* cnt   = (unsigned*)d_ws + 4;          // ws[4]

  hipMemsetAsync(d_ws, 0, 64, stream);            // zero loss accumulator + counter
  vq_main_kernel<<<256, 1024, 0, stream>>>(in, emb, out, loss_acc, cnt);
}